// Round 1
// baseline (105.282 us; speedup 1.0000x reference)
//
#include <hip/hip_runtime.h>
#include <math.h>

#define NPTS 8192
#define NB 4
#define BLK 256
#define Q 8            // queries per thread
#define TILE 512       // ref points staged in LDS per tile (8 KB as float4)

// Kernel 1: for each (batch,dir) and each query point, compute
//   partial[bd][seg][q] = min over refs in segment of (|r|^2 - 2 q.r)
// (|q|^2 added later; min commutes with the +|q|^2 and the clamp.)
__global__ __launch_bounds__(BLK) void chamfer_partial(
    const float* __restrict__ tmpl, const float* __restrict__ src,
    float* __restrict__ partial, int seg_len, int nseg)
{
    __shared__ float4 lds[TILE];
    const int bd  = blockIdx.z;          // 0..7 = b*2 + dir
    const int b   = bd >> 1;
    const int dir = bd & 1;
    const float* qp = (dir ? src : tmpl) + (size_t)b * NPTS * 3;
    const float* rp = (dir ? tmpl : src) + (size_t)b * NPTS * 3;
    const int tid   = threadIdx.x;
    const int qbase = blockIdx.x * (BLK * Q);

    float qx[Q], qy[Q], qz[Q], mn[Q];
#pragma unroll
    for (int k = 0; k < Q; k++) {
        const int qi = qbase + k * BLK + tid;
        qx[k] = qp[3 * qi + 0];
        qy[k] = qp[3 * qi + 1];
        qz[k] = qp[3 * qi + 2];
        mn[k] = 3.4e38f;
    }

    const int seg_start = blockIdx.y * seg_len;
    for (int ts = 0; ts < seg_len; ts += TILE) {
        __syncthreads();
        for (int i = tid; i < TILE; i += BLK) {
            const int ri = seg_start + ts + i;
            const float rx = rp[3 * ri + 0];
            const float ry = rp[3 * ri + 1];
            const float rz = rp[3 * ri + 2];
            lds[i] = make_float4(-2.f * rx, -2.f * ry, -2.f * rz,
                                 rx * rx + ry * ry + rz * rz);
        }
        __syncthreads();
#pragma unroll 4
        for (int j = 0; j < TILE; j++) {
            const float4 r = lds[j];
#pragma unroll
            for (int k = 0; k < Q; k++) {
                float t = fmaf(qx[k], r.x, r.w);
                t = fmaf(qy[k], r.y, t);
                t = fmaf(qz[k], r.z, t);
                mn[k] = fminf(mn[k], t);
            }
        }
    }

    const size_t base = ((size_t)bd * nseg + blockIdx.y) * NPTS;
#pragma unroll
    for (int k = 0; k < Q; k++)
        partial[base + qbase + k * BLK + tid] = mn[k];
}

// Kernel 2: combine segment partials, add |q|^2, clamp, sqrt, global mean.
__global__ __launch_bounds__(BLK) void chamfer_reduce(
    const float* __restrict__ tmpl, const float* __restrict__ src,
    const float* __restrict__ partial, float* __restrict__ out, int nseg)
{
    const int t  = blockIdx.x * BLK + threadIdx.x;  // 0 .. 8*NPTS-1
    const int bd = t >> 13;                         // / NPTS
    const int qi = t & (NPTS - 1);
    const int b  = bd >> 1;
    const int dir = bd & 1;
    const float* qp = (dir ? src : tmpl) + (size_t)b * NPTS * 3;
    const float qx = qp[3 * qi + 0];
    const float qy = qp[3 * qi + 1];
    const float qz = qp[3 * qi + 2];
    const float sq = qx * qx + qy * qy + qz * qz;

    float m = 3.4e38f;
    for (int s = 0; s < nseg; s++)
        m = fminf(m, partial[((size_t)bd * nseg + s) * NPTS + qi]);

    float v = sqrtf(fmaxf(sq + m, 0.f));

    // wave reduction (64 lanes)
#pragma unroll
    for (int off = 32; off > 0; off >>= 1)
        v += __shfl_down(v, off, 64);

    __shared__ float wsum[BLK / 64];
    const int lane = threadIdx.x & 63;
    const int wid  = threadIdx.x >> 6;
    if (lane == 0) wsum[wid] = v;
    __syncthreads();
    if (threadIdx.x == 0) {
        float s = 0.f;
#pragma unroll
        for (int w = 0; w < BLK / 64; w++) s += wsum[w];
        // mean over N (8192) * avg 2 dirs * mean 4 batches = /65536
        atomicAdd(out, s * (1.0f / 65536.0f));
    }
}

extern "C" void kernel_launch(void* const* d_in, const int* in_sizes, int n_in,
                              void* d_out, int out_size, void* d_ws, size_t ws_size,
                              hipStream_t stream) {
    const float* tmpl = (const float*)d_in[0];
    const float* src  = (const float*)d_in[1];
    float* out      = (float*)d_out;
    float* partial  = (float*)d_ws;

    // choose nseg (power of 2) to fit workspace: need 8*nseg*NPTS*4 bytes
    int nseg = 16;
    while (nseg > 1 && (size_t)8 * nseg * NPTS * sizeof(float) > ws_size)
        nseg >>= 1;
    const int seg_len = NPTS / nseg;

    hipMemsetAsync(d_out, 0, sizeof(float), stream);

    dim3 g1(NPTS / (BLK * Q), nseg, 2 * NB);
    chamfer_partial<<<g1, BLK, 0, stream>>>(tmpl, src, partial, seg_len, nseg);

    chamfer_reduce<<<(2 * NB * NPTS) / BLK, BLK, 0, stream>>>(tmpl, src, partial, out, nseg);
}